// Round 10
// baseline (222.888 us; speedup 1.0000x reference)
//
#include <hip/hip_runtime.h>
#include <hip/hip_bf16.h>

#define D_DIM 1024
#define F_DIM 1024
#define NTOK  4096
#define NEXP  8
#define CAP   4096

typedef __attribute__((ext_vector_type(8))) short bf16x8;
typedef __attribute__((ext_vector_type(4))) float f32x4;
typedef __attribute__((ext_vector_type(8))) unsigned short u16x8;

__device__ __forceinline__ unsigned short f2bf(float f) {
    unsigned int u = __float_as_uint(f);
    u = u + 0x7fffu + ((u >> 16) & 1u);
    return (unsigned short)(u >> 16);
}

__device__ __forceinline__ void async_copy16(void* lds, const void* gsrc) {
    __builtin_amdgcn_global_load_lds(
        (const __attribute__((address_space(1))) unsigned int*)gsrc,
        (__attribute__((address_space(3))) unsigned int*)lds, 16, 0, 0);
}

// ---------------- router logits + x->bf16 fold: one wave per token ----------------
__global__ __launch_bounds__(256) void logits_kernel(
    const float* __restrict__ x, const float* __restrict__ rw,
    float* __restrict__ logits, unsigned short* __restrict__ xb)
{
    const int wave = threadIdx.x >> 6, lane = threadIdx.x & 63;
    const int t = blockIdx.x * 4 + wave;
    double s[NEXP];
    #pragma unroll
    for (int e = 0; e < NEXP; ++e) s[e] = 0.0;
    const float* xp = x + (size_t)t * D_DIM;
    unsigned short* xo = xb + (size_t)t * D_DIM;
    for (int kk = 0; kk < D_DIM; kk += 64) {
        float xv = xp[kk + lane];
        xo[kk + lane] = f2bf(xv);          // fold: bf16 conversion of x
        #pragma unroll
        for (int e = 0; e < NEXP; ++e)
            s[e] += (double)xv * (double)rw[e * D_DIM + kk + lane];
    }
    #pragma unroll
    for (int e = 0; e < NEXP; ++e) {
        double v = s[e];
        for (int off = 32; off; off >>= 1) v += __shfl_xor(v, off, 64);
        s[e] = v;
    }
    if (lane == 0) {
        #pragma unroll
        for (int e = 0; e < NEXP; ++e) logits[(size_t)t * NEXP + e] = (float)s[e];
    }
}

// ---------------- assign: top-2 + softmax + expert lists + per-token pair table ----------------
__global__ __launch_bounds__(256) void assign_kernel(
    const float* __restrict__ logits, const float* __restrict__ bias,
    int* counts, int* list, int* pairEP, float* pairW)
{
    __shared__ int lcnt[NEXP];
    __shared__ int lbase[NEXP];
    const int tid = threadIdx.x;
    const int t = blockIdx.x * 256 + tid;
    if (tid < NEXP) lcnt[tid] = 0;
    __syncthreads();

    float lg[NEXP], b2[NEXP];
    #pragma unroll
    for (int e = 0; e < NEXP; ++e) {
        lg[e] = logits[(size_t)t * NEXP + e];
        b2[e] = lg[e] + bias[e];
    }
    int i0 = 0; float b0v = b2[0], l0v = lg[0];
    #pragma unroll
    for (int e = 1; e < NEXP; ++e)
        if (b2[e] > b0v) { b0v = b2[e]; l0v = lg[e]; i0 = e; }
    int i1 = -1; float b1v = 0.f, l1v = 0.f;
    #pragma unroll
    for (int e = 0; e < NEXP; ++e) {
        if (e == i0) continue;
        bool take = (i1 < 0) || (b2[e] > b1v);
        if (take) { i1 = e; b1v = b2[e]; l1v = lg[e]; }
    }
    float m = fmaxf(l0v, l1v);
    float e0 = expf(l0v - m), e1 = expf(l1v - m);
    float inv = 1.0f / (e0 + e1);

    int lp0 = atomicAdd(&lcnt[i0], 1);
    int lp1 = atomicAdd(&lcnt[i1], 1);
    __syncthreads();
    if (tid < NEXP) lbase[tid] = atomicAdd(&counts[tid], lcnt[tid]);
    __syncthreads();

    int p0 = lbase[i0] + lp0;
    int p1 = lbase[i1] + lp1;
    list[i0 * CAP + p0] = t;
    list[i1 * CAP + p1] = t;
    pairEP[2 * t]     = (p0 << 3) | i0;
    pairEP[2 * t + 1] = (p1 << 3) | i1;
    pairW[2 * t]      = e0 * inv;
    pairW[2 * t + 1]  = e1 * inv;
}

// ======== GEMM machinery (r6/r8 compute structure, proven 0-conflict): ========
// ======== BM=128, BN=64, BK=64, single-buffer, stage->sync->compute->sync, ========
// ======== XOR slot swizzle phys = slot ^ (row&7), expert<->XCD affinity (r9). ========
// NEW (r10): B operand reg-staged directly from f32 weights (no cvt pass):
// same pre-swizzled source slot g=(l&7)^(l>>3), same phys LDS slot l&7 --
// involution identical to the async path, so COMPUTE is unchanged.
#define STAGE_A(AB, k0)                                                     \
    do {                                                                    \
        _Pragma("unroll")                                                   \
        for (int i = 0; i < 4; ++i)                                         \
            async_copy16(&AB[(wave * 4 + i) * 512], ap[i] + (k0));          \
    } while (0)

#define STAGE_B_F32(BB, k0)                                                 \
    do {                                                                    \
        _Pragma("unroll")                                                   \
        for (int i = 0; i < 2; ++i) {                                       \
            const float* src = bpf[i] + (k0);                               \
            float4 v0 = *(const float4*)(src);                              \
            float4 v1 = *(const float4*)(src + 4);                          \
            u16x8 rbv;                                                      \
            rbv[0] = f2bf(v0.x); rbv[1] = f2bf(v0.y);                       \
            rbv[2] = f2bf(v0.z); rbv[3] = f2bf(v0.w);                       \
            rbv[4] = f2bf(v1.x); rbv[5] = f2bf(v1.y);                       \
            rbv[6] = f2bf(v1.z); rbv[7] = f2bf(v1.w);                       \
            *(u16x8*)&BB[(wave * 2 + i) * 512 + lane * 8] = rbv;            \
        }                                                                   \
    } while (0)

#define COMPUTE(AB, BB)                                                     \
    do {                                                                    \
        _Pragma("unroll")                                                   \
        for (int kk = 0; kk < 2; ++kk) {                                    \
            bf16x8 af[4], bfv[2];                                           \
            const int phys = (((kk * 4) + (lane >> 4)) ^ (lane & 7)) * 8;   \
            _Pragma("unroll")                                               \
            for (int m = 0; m < 4; ++m)                                     \
                af[m] = *(const bf16x8*)&AB[(wr * 64 + m * 16 + (lane & 15)) * 64 + phys]; \
            _Pragma("unroll")                                               \
            for (int n = 0; n < 2; ++n)                                     \
                bfv[n] = *(const bf16x8*)&BB[(wc * 32 + n * 16 + (lane & 15)) * 64 + phys]; \
            _Pragma("unroll")                                               \
            for (int m = 0; m < 4; ++m)                                     \
                _Pragma("unroll")                                           \
                for (int n = 0; n < 2; ++n)                                 \
                    acc[m][n] = __builtin_amdgcn_mfma_f32_16x16x32_bf16(af[m], bfv[n], acc[m][n], 0, 0, 0); \
        }                                                                   \
    } while (0)

// ---------------- grouped GEMM1: H = gelu(Xg @ W1_e^T), bf16 out ----------------
__global__ __launch_bounds__(256) void gemm1_kernel(
    const unsigned short* __restrict__ xb,
    const float* __restrict__ w1,
    const int* __restrict__ counts,
    const int* __restrict__ list,
    unsigned short* __restrict__ H)
{
    const int bid = blockIdx.x;
    const int e  = bid & 7;          // XCD affinity: b%8 -> XCD
    const int s  = bid >> 3;         // 512 slots: rb*16 + nx
    const int rb = s >> 4;
    const int ne = counts[e];
    if (rb * 128 >= ne) return;
    const int row0 = rb * 128;
    const int n0 = (s & 15) * 64;
    int hbase = 0;
    #pragma unroll
    for (int ee = 0; ee < NEXP; ++ee) if (ee < e) hbase += counts[ee];

    __shared__ __align__(16) unsigned short As[128 * 64];
    __shared__ __align__(16) unsigned short Bs[64 * 64];
    __shared__ int toks[128];

    const int tid = threadIdx.x;
    if (tid < 128) {
        int i = row0 + tid;
        if (i >= ne) i = ne - 1;
        toks[tid] = list[e * CAP + i];
    }
    __syncthreads();

    const int wave = tid >> 6, lane = tid & 63;
    const int wr = wave >> 1, wc = wave & 1;

    const int lr  = lane >> 3;
    const int s8  = (lane & 7) ^ lr;       // pre-swizzled logical slot
    const unsigned short* ap[4];
    const float* bpf[2];
    const float* wbase = w1 + (size_t)e * F_DIM * D_DIM;
    #pragma unroll
    for (int i = 0; i < 4; ++i)
        ap[i] = xb + (size_t)toks[wave * 32 + i * 8 + lr] * D_DIM + s8 * 8;
    #pragma unroll
    for (int i = 0; i < 2; ++i)
        bpf[i] = wbase + (size_t)(n0 + wave * 16 + i * 8 + lr) * D_DIM + s8 * 8;

    f32x4 acc[4][2];
    #pragma unroll
    for (int m = 0; m < 4; ++m)
        #pragma unroll
        for (int n = 0; n < 2; ++n) acc[m][n] = (f32x4){0.f, 0.f, 0.f, 0.f};

    for (int k0 = 0; k0 < D_DIM; k0 += 64) {
        STAGE_A(As, k0);
        STAGE_B_F32(Bs, k0);
        __syncthreads();
        COMPUTE(As, Bs);
        __syncthreads();
    }

    #pragma unroll
    for (int m = 0; m < 4; ++m) {
        #pragma unroll
        for (int j = 0; j < 4; ++j) {
            int ri = wr * 64 + m * 16 + (lane >> 4) * 4 + j;
            int i = row0 + ri;
            if (i < ne) {
                unsigned short* hp = H + (size_t)(hbase + i) * F_DIM + n0 + wc * 32;
                #pragma unroll
                for (int n = 0; n < 2; ++n) {
                    float v = acc[m][n][j];
                    float g = 0.5f * v * (1.0f + erff(v * 0.70710678118654752f));
                    hp[n * 16 + (lane & 15)] = f2bf(g);
                }
            }
        }
    }
}

// ---------------- grouped GEMM2: O2 = H @ W2_e^T (plain f32 stores) ----------------
__global__ __launch_bounds__(256) void gemm2_kernel(
    const unsigned short* __restrict__ H,
    const float* __restrict__ w2,
    const int* __restrict__ counts,
    float* __restrict__ O2)
{
    const int bid = blockIdx.x;
    const int e  = bid & 7;          // XCD affinity: b%8 -> XCD
    const int s  = bid >> 3;
    const int rb = s >> 4;
    const int ne = counts[e];
    if (rb * 128 >= ne) return;
    const int row0 = rb * 128;
    const int n0 = (s & 15) * 64;
    int hbase = 0;
    #pragma unroll
    for (int ee = 0; ee < NEXP; ++ee) if (ee < e) hbase += counts[ee];

    __shared__ __align__(16) unsigned short As[128 * 64];
    __shared__ __align__(16) unsigned short Bs[64 * 64];

    const int tid = threadIdx.x;
    const int wave = tid >> 6, lane = tid & 63;
    const int wr = wave >> 1, wc = wave & 1;

    const int lr  = lane >> 3;
    const int s8  = (lane & 7) ^ lr;
    const unsigned short* ap[4];
    const float* bpf[2];
    const float* wbase = w2 + (size_t)e * D_DIM * F_DIM;
    #pragma unroll
    for (int i = 0; i < 4; ++i)
        ap[i] = H + (size_t)(hbase + row0 + wave * 32 + i * 8 + lr) * F_DIM + s8 * 8;
    #pragma unroll
    for (int i = 0; i < 2; ++i)
        bpf[i] = wbase + (size_t)(n0 + wave * 16 + i * 8 + lr) * F_DIM + s8 * 8;

    f32x4 acc[4][2];
    #pragma unroll
    for (int m = 0; m < 4; ++m)
        #pragma unroll
        for (int n = 0; n < 2; ++n) acc[m][n] = (f32x4){0.f, 0.f, 0.f, 0.f};

    for (int k0 = 0; k0 < F_DIM; k0 += 64) {
        STAGE_A(As, k0);
        STAGE_B_F32(Bs, k0);
        __syncthreads();
        COMPUTE(As, Bs);
        __syncthreads();
    }

    #pragma unroll
    for (int m = 0; m < 4; ++m) {
        #pragma unroll
        for (int j = 0; j < 4; ++j) {
            int ri = wr * 64 + m * 16 + (lane >> 4) * 4 + j;
            int i = row0 + ri;
            if (i < ne) {
                float* op = O2 + (size_t)(hbase + i) * D_DIM + n0 + wc * 32;
                #pragma unroll
                for (int n = 0; n < 2; ++n)
                    op[n * 16 + (lane & 15)] = acc[m][n][j];
            }
        }
    }
}

// ---------------- combine: out[t] = w0*O2[row0] + w1*O2[row1] ----------------
__global__ __launch_bounds__(256) void combine_kernel(
    const float* __restrict__ O2, const int* __restrict__ counts,
    const int* __restrict__ pairEP, const float* __restrict__ pairW,
    float* __restrict__ out)
{
    const int t = blockIdx.x;
    const int tid = threadIdx.x;
    int offs[NEXP];
    int a = 0;
    #pragma unroll
    for (int e = 0; e < NEXP; ++e) { offs[e] = a; a += counts[e]; }
    int ep0 = pairEP[2 * t], ep1 = pairEP[2 * t + 1];
    float w0 = pairW[2 * t], w1 = pairW[2 * t + 1];
    int e0 = ep0 & 7, e1 = ep1 & 7, o0 = 0, o1 = 0;
    #pragma unroll
    for (int e = 0; e < NEXP; ++e) {
        if (e == e0) o0 = offs[e];
        if (e == e1) o1 = offs[e];
    }
    size_t r0 = (size_t)(o0 + (ep0 >> 3)) * D_DIM;
    size_t r1 = (size_t)(o1 + (ep1 >> 3)) * D_DIM;
    float4 va = *(const float4*)(O2 + r0 + tid * 4);
    float4 vb = *(const float4*)(O2 + r1 + tid * 4);
    float4 r;
    r.x = w0 * va.x + w1 * vb.x;
    r.y = w0 * va.y + w1 * vb.y;
    r.z = w0 * va.z + w1 * vb.z;
    r.w = w0 * va.w + w1 * vb.w;
    *(float4*)(out + (size_t)t * D_DIM + tid * 4) = r;
}

extern "C" void kernel_launch(void* const* d_in, const int* in_sizes, int n_in,
                              void* d_out, int out_size, void* d_ws, size_t ws_size,
                              hipStream_t stream)
{
    const float* x    = (const float*)d_in[0];
    const float* bias = (const float*)d_in[1];
    const float* rw   = (const float*)d_in[2];
    const float* w1   = (const float*)d_in[3];
    const float* w2   = (const float*)d_in[4];
    float* out = (float*)d_out;

    char* ws = (char*)d_ws;
    // Layout: xb (8.4MB) | Hb (17MB) | O2 (34MB) | tail
    unsigned short* xb = (unsigned short*)(ws);
    unsigned short* Hb = (unsigned short*)(ws + 8388608);
    float*          O2 = (float*)        (ws + 8388608 + 17039360);
    char* tail = ws + 8388608 + 17039360 + 34078720;
    float* logits = (float*)(tail);
    int*   list   = (int*)(tail + 131072);
    int*   pairEP = (int*)(tail + 262144);
    float* pairW  = (float*)(tail + 294912);
    int*   counts = (int*)(tail + 327680);

    hipMemsetAsync(counts, 0, 64, stream);

    logits_kernel<<<NTOK / 4, 256, 0, stream>>>(x, rw, logits, xb);
    assign_kernel<<<NTOK / 256, 256, 0, stream>>>(logits, bias, counts, list, pairEP, pairW);
    gemm1_kernel<<<4096, 256, 0, stream>>>(xb, w1, counts, list, Hb);
    gemm2_kernel<<<4096, 256, 0, stream>>>(Hb, w2, counts, O2);
    combine_kernel<<<NTOK, 256, 0, stream>>>(O2, counts, pairEP, pairW, out);
}

// Round 11
// 210.378 us; speedup vs baseline: 1.0595x; 1.0595x over previous
//
#include <hip/hip_runtime.h>
#include <hip/hip_bf16.h>

#define D_DIM 1024
#define F_DIM 1024
#define NTOK  4096
#define NEXP  8
#define CAP   4096

typedef __attribute__((ext_vector_type(8))) short bf16x8;
typedef __attribute__((ext_vector_type(4))) float f32x4;
typedef __attribute__((ext_vector_type(8))) unsigned short u16x8;
typedef __attribute__((ext_vector_type(4))) unsigned short u16x4;

__device__ __forceinline__ unsigned short f2bf(float f) {
    unsigned int u = __float_as_uint(f);
    u = u + 0x7fffu + ((u >> 16) & 1u);
    return (unsigned short)(u >> 16);
}

__device__ __forceinline__ float bf2f(unsigned short v) {
    return __uint_as_float(((unsigned int)v) << 16);
}

__device__ __forceinline__ void async_copy16(void* lds, const void* gsrc) {
    __builtin_amdgcn_global_load_lds(
        (const __attribute__((address_space(1))) unsigned int*)gsrc,
        (__attribute__((address_space(3))) unsigned int*)lds, 16, 0, 0);
}

// ---------------- weight f32 -> bf16 conversion (w1+w2, 8 elems/thread) ----------------
#define NW_GRP (NEXP * F_DIM * D_DIM / 8)
__global__ __launch_bounds__(256) void cvtw_kernel(
    const float* __restrict__ w1, const float* __restrict__ w2,
    unsigned short* __restrict__ w1b, unsigned short* __restrict__ w2b)
{
    long g = (long)blockIdx.x * 256 + threadIdx.x;
    const float* src; unsigned short* dst; long o;
    if (g < NW_GRP) { src = w1; dst = w1b; o = g; }
    else            { src = w2; dst = w2b; o = g - NW_GRP; }
    size_t i = (size_t)o * 8;
    float4 a = *(const float4*)(src + i);
    float4 b = *(const float4*)(src + i + 4);
    u16x8 r;
    r[0] = f2bf(a.x); r[1] = f2bf(a.y); r[2] = f2bf(a.z); r[3] = f2bf(a.w);
    r[4] = f2bf(b.x); r[5] = f2bf(b.y); r[6] = f2bf(b.z); r[7] = f2bf(b.w);
    *(u16x8*)(dst + i) = r;
}

// ---------------- router logits + x->bf16 fold: one wave per token ----------------
__global__ __launch_bounds__(256) void logits_kernel(
    const float* __restrict__ x, const float* __restrict__ rw,
    float* __restrict__ logits, unsigned short* __restrict__ xb)
{
    const int wave = threadIdx.x >> 6, lane = threadIdx.x & 63;
    const int t = blockIdx.x * 4 + wave;
    double s[NEXP];
    #pragma unroll
    for (int e = 0; e < NEXP; ++e) s[e] = 0.0;
    const float* xp = x + (size_t)t * D_DIM;
    unsigned short* xo = xb + (size_t)t * D_DIM;
    for (int kk = 0; kk < D_DIM; kk += 64) {
        float xv = xp[kk + lane];
        xo[kk + lane] = f2bf(xv);          // fold: bf16 conversion of x
        #pragma unroll
        for (int e = 0; e < NEXP; ++e)
            s[e] += (double)xv * (double)rw[e * D_DIM + kk + lane];
    }
    #pragma unroll
    for (int e = 0; e < NEXP; ++e) {
        double v = s[e];
        for (int off = 32; off; off >>= 1) v += __shfl_xor(v, off, 64);
        s[e] = v;
    }
    if (lane == 0) {
        #pragma unroll
        for (int e = 0; e < NEXP; ++e) logits[(size_t)t * NEXP + e] = (float)s[e];
    }
}

// ---------------- assign: top-2 + softmax + expert lists + per-token pair table ----------------
__global__ __launch_bounds__(256) void assign_kernel(
    const float* __restrict__ logits, const float* __restrict__ bias,
    int* counts, int* list, int* pairEP, float* pairW)
{
    __shared__ int lcnt[NEXP];
    __shared__ int lbase[NEXP];
    const int tid = threadIdx.x;
    const int t = blockIdx.x * 256 + tid;
    if (tid < NEXP) lcnt[tid] = 0;
    __syncthreads();

    float lg[NEXP], b2[NEXP];
    #pragma unroll
    for (int e = 0; e < NEXP; ++e) {
        lg[e] = logits[(size_t)t * NEXP + e];
        b2[e] = lg[e] + bias[e];
    }
    int i0 = 0; float b0v = b2[0], l0v = lg[0];
    #pragma unroll
    for (int e = 1; e < NEXP; ++e)
        if (b2[e] > b0v) { b0v = b2[e]; l0v = lg[e]; i0 = e; }
    int i1 = -1; float b1v = 0.f, l1v = 0.f;
    #pragma unroll
    for (int e = 0; e < NEXP; ++e) {
        if (e == i0) continue;
        bool take = (i1 < 0) || (b2[e] > b1v);
        if (take) { i1 = e; b1v = b2[e]; l1v = lg[e]; }
    }
    float m = fmaxf(l0v, l1v);
    float e0 = expf(l0v - m), e1 = expf(l1v - m);
    float inv = 1.0f / (e0 + e1);

    int lp0 = atomicAdd(&lcnt[i0], 1);
    int lp1 = atomicAdd(&lcnt[i1], 1);
    __syncthreads();
    if (tid < NEXP) lbase[tid] = atomicAdd(&counts[tid], lcnt[tid]);
    __syncthreads();

    int p0 = lbase[i0] + lp0;
    int p1 = lbase[i1] + lp1;
    list[i0 * CAP + p0] = t;
    list[i1 * CAP + p1] = t;
    pairEP[2 * t]     = (p0 << 3) | i0;
    pairEP[2 * t + 1] = (p1 << 3) | i1;
    pairW[2 * t]      = e0 * inv;
    pairW[2 * t + 1]  = e1 * inv;
}

// ======== GEMM machinery (EXACT r9 structure, measured best): ========
// ======== BM=128, BN=64, BK=64, single-buffer, stage->sync->compute->sync, ========
// ======== XOR slot swizzle phys = slot ^ (row&7) (0 conflicts), ========
// ======== expert<->XCD affinity: block b = slot*8 + e (b%8 -> XCD e). ========
#define STAGE(AB, BB, k0)                                                   \
    do {                                                                    \
        _Pragma("unroll")                                                   \
        for (int i = 0; i < 4; ++i)                                         \
            async_copy16(&AB[(wave * 4 + i) * 512], ap[i] + (k0));          \
        _Pragma("unroll")                                                   \
        for (int i = 0; i < 2; ++i)                                         \
            async_copy16(&BB[(wave * 2 + i) * 512], bp_[i] + (k0));         \
    } while (0)

#define COMPUTE(AB, BB)                                                     \
    do {                                                                    \
        _Pragma("unroll")                                                   \
        for (int kk = 0; kk < 2; ++kk) {                                    \
            bf16x8 af[4], bfv[2];                                           \
            const int phys = (((kk * 4) + (lane >> 4)) ^ (lane & 7)) * 8;   \
            _Pragma("unroll")                                               \
            for (int m = 0; m < 4; ++m)                                     \
                af[m] = *(const bf16x8*)&AB[(wr * 64 + m * 16 + (lane & 15)) * 64 + phys]; \
            _Pragma("unroll")                                               \
            for (int n = 0; n < 2; ++n)                                     \
                bfv[n] = *(const bf16x8*)&BB[(wc * 32 + n * 16 + (lane & 15)) * 64 + phys]; \
            _Pragma("unroll")                                               \
            for (int m = 0; m < 4; ++m)                                     \
                _Pragma("unroll")                                           \
                for (int n = 0; n < 2; ++n)                                 \
                    acc[m][n] = __builtin_amdgcn_mfma_f32_16x16x32_bf16(af[m], bfv[n], acc[m][n], 0, 0, 0); \
        }                                                                   \
    } while (0)

// ---------------- grouped GEMM1: H = gelu(Xg @ W1_e^T), bf16 out ----------------
__global__ __launch_bounds__(256) void gemm1_kernel(
    const unsigned short* __restrict__ xb,
    const unsigned short* __restrict__ w1b,
    const int* __restrict__ counts,
    const int* __restrict__ list,
    unsigned short* __restrict__ H)
{
    const int bid = blockIdx.x;
    const int e  = bid & 7;          // XCD affinity: b%8 -> XCD
    const int s  = bid >> 3;         // 512 slots: rb*16 + nx
    const int rb = s >> 4;
    const int ne = counts[e];
    if (rb * 128 >= ne) return;
    const int row0 = rb * 128;
    const int n0 = (s & 15) * 64;
    int hbase = 0;
    #pragma unroll
    for (int ee = 0; ee < NEXP; ++ee) if (ee < e) hbase += counts[ee];

    __shared__ __align__(16) unsigned short As[128 * 64];
    __shared__ __align__(16) unsigned short Bs[64 * 64];
    __shared__ int toks[128];

    const int tid = threadIdx.x;
    if (tid < 128) {
        int i = row0 + tid;
        if (i >= ne) i = ne - 1;
        toks[tid] = list[e * CAP + i];
    }
    __syncthreads();

    const int wave = tid >> 6, lane = tid & 63;
    const int wr = wave >> 1, wc = wave & 1;

    const int lr  = lane >> 3;
    const int swz = ((lane & 7) ^ lr) * 8;
    const unsigned short* ap[4];
    const unsigned short* bp_[2];
    const unsigned short* wbase = w1b + (size_t)e * F_DIM * D_DIM;
    #pragma unroll
    for (int i = 0; i < 4; ++i)
        ap[i] = xb + (size_t)toks[wave * 32 + i * 8 + lr] * D_DIM + swz;
    #pragma unroll
    for (int i = 0; i < 2; ++i)
        bp_[i] = wbase + (size_t)(n0 + wave * 16 + i * 8 + lr) * D_DIM + swz;

    f32x4 acc[4][2];
    #pragma unroll
    for (int m = 0; m < 4; ++m)
        #pragma unroll
        for (int n = 0; n < 2; ++n) acc[m][n] = (f32x4){0.f, 0.f, 0.f, 0.f};

    for (int k0 = 0; k0 < D_DIM; k0 += 64) {
        STAGE(As, Bs, k0);
        __syncthreads();
        COMPUTE(As, Bs);
        __syncthreads();
    }

    #pragma unroll
    for (int m = 0; m < 4; ++m) {
        #pragma unroll
        for (int j = 0; j < 4; ++j) {
            int ri = wr * 64 + m * 16 + (lane >> 4) * 4 + j;
            int i = row0 + ri;
            if (i < ne) {
                unsigned short* hp = H + (size_t)(hbase + i) * F_DIM + n0 + wc * 32;
                #pragma unroll
                for (int n = 0; n < 2; ++n) {
                    float v = acc[m][n][j];
                    float g = 0.5f * v * (1.0f + erff(v * 0.70710678118654752f));
                    hp[n * 16 + (lane & 15)] = f2bf(g);
                }
            }
        }
    }
}

// ---------------- grouped GEMM2: O2 = H @ W2_e^T (bf16 stores, NO atomics) ----------------
__global__ __launch_bounds__(256) void gemm2_kernel(
    const unsigned short* __restrict__ H,
    const unsigned short* __restrict__ w2b,
    const int* __restrict__ counts,
    unsigned short* __restrict__ O2b)
{
    const int bid = blockIdx.x;
    const int e  = bid & 7;          // XCD affinity: b%8 -> XCD
    const int s  = bid >> 3;
    const int rb = s >> 4;
    const int ne = counts[e];
    if (rb * 128 >= ne) return;
    const int row0 = rb * 128;
    const int n0 = (s & 15) * 64;
    int hbase = 0;
    #pragma unroll
    for (int ee = 0; ee < NEXP; ++ee) if (ee < e) hbase += counts[ee];

    __shared__ __align__(16) unsigned short As[128 * 64];
    __shared__ __align__(16) unsigned short Bs[64 * 64];

    const int tid = threadIdx.x;
    const int wave = tid >> 6, lane = tid & 63;
    const int wr = wave >> 1, wc = wave & 1;

    const int lr  = lane >> 3;
    const int swz = ((lane & 7) ^ lr) * 8;
    const unsigned short* ap[4];
    const unsigned short* bp_[2];
    const unsigned short* wbase = w2b + (size_t)e * D_DIM * F_DIM;
    #pragma unroll
    for (int i = 0; i < 4; ++i)
        ap[i] = H + (size_t)(hbase + row0 + wave * 32 + i * 8 + lr) * F_DIM + swz;
    #pragma unroll
    for (int i = 0; i < 2; ++i)
        bp_[i] = wbase + (size_t)(n0 + wave * 16 + i * 8 + lr) * F_DIM + swz;

    f32x4 acc[4][2];
    #pragma unroll
    for (int m = 0; m < 4; ++m)
        #pragma unroll
        for (int n = 0; n < 2; ++n) acc[m][n] = (f32x4){0.f, 0.f, 0.f, 0.f};

    for (int k0 = 0; k0 < F_DIM; k0 += 64) {
        STAGE(As, Bs, k0);
        __syncthreads();
        COMPUTE(As, Bs);
        __syncthreads();
    }

    #pragma unroll
    for (int m = 0; m < 4; ++m) {
        #pragma unroll
        for (int j = 0; j < 4; ++j) {
            int ri = wr * 64 + m * 16 + (lane >> 4) * 4 + j;
            int i = row0 + ri;
            if (i < ne) {
                unsigned short* op = O2b + (size_t)(hbase + i) * D_DIM + n0 + wc * 32;
                #pragma unroll
                for (int n = 0; n < 2; ++n)
                    op[n * 16 + (lane & 15)] = f2bf(acc[m][n][j]);
            }
        }
    }
}

// ---------------- combine: out[t] = w0*O2[row0] + w1*O2[row1] (bf16 reads) ----------------
__global__ __launch_bounds__(256) void combine_kernel(
    const unsigned short* __restrict__ O2b, const int* __restrict__ counts,
    const int* __restrict__ pairEP, const float* __restrict__ pairW,
    float* __restrict__ out)
{
    const int t = blockIdx.x;
    const int tid = threadIdx.x;
    int offs[NEXP];
    int a = 0;
    #pragma unroll
    for (int e = 0; e < NEXP; ++e) { offs[e] = a; a += counts[e]; }
    int ep0 = pairEP[2 * t], ep1 = pairEP[2 * t + 1];
    float w0 = pairW[2 * t], w1 = pairW[2 * t + 1];
    int e0 = ep0 & 7, e1 = ep1 & 7, o0 = 0, o1 = 0;
    #pragma unroll
    for (int e = 0; e < NEXP; ++e) {
        if (e == e0) o0 = offs[e];
        if (e == e1) o1 = offs[e];
    }
    size_t r0 = (size_t)(o0 + (ep0 >> 3)) * D_DIM;
    size_t r1 = (size_t)(o1 + (ep1 >> 3)) * D_DIM;
    u16x4 va = *(const u16x4*)(O2b + r0 + tid * 4);
    u16x4 vb = *(const u16x4*)(O2b + r1 + tid * 4);
    float4 r;
    r.x = w0 * bf2f(va[0]) + w1 * bf2f(vb[0]);
    r.y = w0 * bf2f(va[1]) + w1 * bf2f(vb[1]);
    r.z = w0 * bf2f(va[2]) + w1 * bf2f(vb[2]);
    r.w = w0 * bf2f(va[3]) + w1 * bf2f(vb[3]);
    *(float4*)(out + (size_t)t * D_DIM + tid * 4) = r;
}

extern "C" void kernel_launch(void* const* d_in, const int* in_sizes, int n_in,
                              void* d_out, int out_size, void* d_ws, size_t ws_size,
                              hipStream_t stream)
{
    const float* x    = (const float*)d_in[0];
    const float* bias = (const float*)d_in[1];
    const float* rw   = (const float*)d_in[2];
    const float* w1   = (const float*)d_in[3];
    const float* w2   = (const float*)d_in[4];
    float* out = (float*)d_out;

    char* ws = (char*)d_ws;
    // Layout: w1b 16.8M | w2b 16.8M | xb 8.4M | Hb 17M | O2b 17M | tail
    unsigned short* w1b = (unsigned short*)(ws);
    unsigned short* w2b = (unsigned short*)(ws + 16777216);
    unsigned short* xb  = (unsigned short*)(ws + 33554432);
    unsigned short* Hb  = (unsigned short*)(ws + 41943040);
    unsigned short* O2b = (unsigned short*)(ws + 58982400);
    char* tail = ws + 76021760;
    float* logits = (float*)(tail);
    int*   list   = (int*)(tail + 131072);
    int*   pairEP = (int*)(tail + 262144);
    float* pairW  = (float*)(tail + 294912);
    int*   counts = (int*)(tail + 327680);

    hipMemsetAsync(counts, 0, 64, stream);

    cvtw_kernel<<<2 * NW_GRP / 256, 256, 0, stream>>>(w1, w2, w1b, w2b);
    logits_kernel<<<NTOK / 4, 256, 0, stream>>>(x, rw, logits, xb);
    assign_kernel<<<NTOK / 256, 256, 0, stream>>>(logits, bias, counts, list, pairEP, pairW);
    gemm1_kernel<<<4096, 256, 0, stream>>>(xb, w1b, counts, list, Hb);
    gemm2_kernel<<<4096, 256, 0, stream>>>(Hb, w2b, counts, O2b);
    combine_kernel<<<NTOK, 256, 0, stream>>>(O2b, counts, pairEP, pairW, out);
}